// Round 18
// baseline (36.295 us; speedup 1.0000x reference)
//
#include <hip/hip_runtime.h>
#include <stdint.h>

#define B_TOT 2048
#define H_DIM 4096
#define R_DIM 64
#define NA_DIM 64
#define NS 32                    // k-slices (KS=128), grid 2048
#define KS (H_DIM / NS)          // 128 k per slice
#define LW 68                    // X_lds row stride in u32 words (64 + 4 pad)
#define X_ELEMS (B_TOT*H_DIM)
#define W_ELEMS (B_TOT)
#define A_ELEMS (NA_DIM*H_DIM*R_DIM)

typedef _Float16 f16x8 __attribute__((ext_vector_type(8)));
typedef float    f32x4 __attribute__((ext_vector_type(4)));

__device__ __forceinline__ uint32_t pkf16(float a, float b) {
  auto h = __builtin_amdgcn_cvt_pkrtz(a, b);   // exact: inputs fp16-representable
  union { decltype(h) v; uint32_t u; } cv; cv.v = h; return cv.u;
}

// async global->LDS, 16 B per lane; LDS dest = wave-uniform base + lane*16
#define GLDS16(gp, lp) __builtin_amdgcn_global_load_lds(                         \
    (const __attribute__((address_space(1))) uint32_t*)(const void*)(gp),        \
    (__attribute__((address_space(3))) uint32_t*)(lp), 16, 0, 0)

// One-time binning: block a (1 wave) ballot-scans wids -> cnt[a] + ordered
// list; tail-pads bin row to max(ceil16(n),16) with index 0 so the main
// kernel can issue group-0/1 bin+x loads BEFORE cnt arrives (values only
// consumed under the n-guard; padded entries point at valid x row 0).
__global__ __launch_bounds__(64)
void k_bin64(const int* __restrict__ wids, int* __restrict__ cnt,
             uint16_t* __restrict__ bin) {
  const int a = blockIdx.x;
  const int l = threadIdx.x;
  int v[32];
#pragma unroll
  for (int i = 0; i < 32; ++i) v[i] = wids[i * 64 + l];
  int c = 0;
#pragma unroll
  for (int i = 0; i < 32; ++i) {
    bool hit = (v[i] == a);
    unsigned long long m = __ballot(hit);
    if (hit) bin[a * B_TOT + c + __popcll(m & ((1ull << l) - 1ull))] =
        (uint16_t)(i * 64 + l);
    c += __popcll(m);
  }
  int top = (c + 15) & ~15; if (top < 16) top = 16;
  for (int p = c + l; p < top; p += 64) bin[a * B_TOT + p] = 0;
  if (l == 0) cnt[a] = c;
}

// Block (adapter a = bx&63, k-slice ks = bx>>6): GEMM X_a[n x 128] @
// A_a[128 x 64] -> f16 partial slice ks.
// A-slice (32 KB f32 [k][r]) staged via global_load_lds: 8 insts/thread,
// zero VGPR, ALL bytes in flight at once (fixes the serial 4-batch register
// gather r17's VGPR=24 exposed). afr[] built from one-time ds_read_b32s.
// Group-0 bin+x loads issue at cycle 0 (padded bin, no cnt dependency).
// X_lds double-buffered, one barrier per group. Maps identical to verified
// r15-r17 kernels: frag k-map (kg=l>>4, j), C/D col=l&15 (->r=w*16+col),
// row=(l>>4)*4+i (->sample).
__global__ __launch_bounds__(256)
void k_lora_mfma6(const float* __restrict__ x, const int* __restrict__ cnt,
                  const uint16_t* __restrict__ bin, const float* __restrict__ A,
                  uint16_t* __restrict__ part) {
  __shared__ __align__(16) float    AL[KS * R_DIM];       // 32 KB f32 [k][r]
  __shared__ __align__(16) uint32_t X_lds[2 * 16 * LW];   // 8.7 KB dbuf

  const int bx = blockIdx.x;
  const int a = bx & 63, ks = bx >> 6;
  const int t = threadIdx.x;
  const int w = t >> 6, l = t & 63;
  const int ml = l & 15;    // X-row / D-col lane index
  const int kg = l >> 4;    // k-group within fragment
  const int m_st = t >> 4, q_st = t & 15;   // X staging roles

  // ---- issue A-slice async staging (independent, all in flight) ----
  const float* Ag = A + ((size_t)a * H_DIM + (size_t)ks * KS) * R_DIM;
#pragma unroll
  for (int i = 0; i < 8; ++i) {
    const int off = (i * 256 + t) * 4;      // f32 words, 16 B per lane
    GLDS16(Ag + off, AL + off);
  }

  // ---- concurrent: bin g0 preload, cnt, x g0 loads ----
  const uint16_t* mybin = bin + a * B_TOT;
  const int b0 = mybin[m_st];               // padded-safe
  const int n = cnt[a];
  const float* xr0 = x + (size_t)b0 * H_DIM + (size_t)ks * KS;
  float4 u0 = *(const float4*)(xr0 + q_st * 8);
  float4 u1 = *(const float4*)(xr0 + q_st * 8 + 4);
  {
    uint4 pw;
    pw.x = pkf16(u0.x, u0.y); pw.y = pkf16(u0.z, u0.w);
    pw.z = pkf16(u1.x, u1.y); pw.w = pkf16(u1.z, u1.w);
    *(uint4*)&X_lds[m_st * LW + q_st * 4] = pw;
  }
  __syncthreads();   // A staged + X g0 visible

  // ---- afr from LDS (one-time, ~32 ds_read_b32 + 16 cvt) ----
  f16x8 afr[4];
#pragma unroll
  for (int kst = 0; kst < 4; ++kst) {
    const float* p = AL + (size_t)(kst * 32 + kg * 8) * R_DIM + (w * 16 + ml);
    float v0 = p[0],     v1 = p[64],    v2 = p[2*64],  v3 = p[3*64];
    float v4 = p[4*64],  v5 = p[5*64],  v6 = p[6*64],  v7 = p[7*64];
    union { uint4 u; f16x8 h; } cv;
    cv.u.x = pkf16(v0, v1); cv.u.y = pkf16(v2, v3);
    cv.u.z = pkf16(v4, v5); cv.u.w = pkf16(v6, v7);
    afr[kst] = cv.h;
  }

  for (int mg = 0; ; ++mg) {
    const int base = mg * 16;
    const int buf = (mg & 1) * (16 * LW);

    // ---- compute group mg from buf ----
    f32x4 acc = {0.f, 0.f, 0.f, 0.f};
#pragma unroll
    for (int kst = 0; kst < 4; ++kst) {
      f16x8 xf = *(const f16x8*)(X_lds + buf + ml * LW + kst * 16 + kg * 4);
      acc = __builtin_amdgcn_mfma_f32_16x16x32_f16(xf, afr[kst], acc, 0, 0, 0);
    }
#pragma unroll
    for (int i = 0; i < 4; ++i) {
      const int sidx = base + kg * 4 + i;
      if (sidx < n) {
        union { _Float16 h; uint16_t u; } cv; cv.h = (_Float16)acc[i];
        part[(size_t)ks * (B_TOT * R_DIM) +
             (size_t)mybin[sidx] * R_DIM + w * 16 + ml] = cv.u;
      }
    }

    if ((mg + 1) * 16 >= n) break;
    // ---- stage group mg+1 into other buffer ----
    {
      int sidx = (mg + 1) * 16 + m_st; if (sidx > n - 1) sidx = n - 1;
      const float* xr = x + (size_t)mybin[sidx] * H_DIM + (size_t)ks * KS;
      float4 a0 = *(const float4*)(xr + q_st * 8);
      float4 a1 = *(const float4*)(xr + q_st * 8 + 4);
      uint4 pw;
      pw.x = pkf16(a0.x, a0.y); pw.y = pkf16(a0.z, a0.w);
      pw.z = pkf16(a1.x, a1.y); pw.w = pkf16(a1.z, a1.w);
      *(uint4*)&X_lds[(buf ^ (16 * LW)) + m_st * LW + q_st * 4] = pw;
    }
    __syncthreads();   // next buf ready (readers of old buf are done: same barrier)
  }
}

// 512 blocks, one f32 output element per thread (was 128 blocks / 0.5 waves/CU).
__global__ __launch_bounds__(256)
void k_reduce32v(const uint16_t* __restrict__ part, float* __restrict__ out) {
  const int t = blockIdx.x * 256 + threadIdx.x;   // 131072 threads
  float v = 0.f;
#pragma unroll
  for (int p = 0; p < NS; ++p) {
    union { uint16_t u; _Float16 h; } c;
    c.u = part[(size_t)p * (B_TOT * R_DIM) + t];
    v += (float)c.h;
  }
  out[t] = v;
}

// No-workspace fallback (proven-correct round-6 naive kernel).
__global__ __launch_bounds__(256)
void k_naive_f32(const float* __restrict__ x, const int* __restrict__ wids,
                 const float* __restrict__ A, float* __restrict__ out) {
  __shared__ float red[256];
  const int b = blockIdx.x;
  const int t = threadIdx.x;
  const int r = t & 63;
  const int q = t >> 6;
  const int a = wids[b];
  const float* xrow = x + (size_t)b * H_DIM;
  const float* Aad  = A + (size_t)a * H_DIM * R_DIM + r;
  float acc = 0.f;
  const int h0 = q * (H_DIM / 4), h1 = h0 + (H_DIM / 4);
  for (int h = h0; h < h1; ++h) acc += xrow[h] * Aad[(size_t)h * R_DIM];
  red[t] = acc;
  __syncthreads();
  if (t < 64) {
    out[(size_t)b * R_DIM + t] = red[t] + red[t + 64] + red[t + 128] + red[t + 192];
  }
}

extern "C" void kernel_launch(void* const* d_in, const int* in_sizes, int n_in,
                              void* d_out, int out_size, void* d_ws, size_t ws_size,
                              hipStream_t stream) {
  // Identify inputs by element count — robust to any ordering.
  const void* px = nullptr; const void* pw = nullptr; const void* pa = nullptr;
  for (int i = 0; i < n_in; ++i) {
    if (in_sizes[i] == X_ELEMS) px = d_in[i];
    else if (in_sizes[i] == W_ELEMS) pw = d_in[i];
    else if (in_sizes[i] == A_ELEMS) pa = d_in[i];
  }
  if (!px || !pw || !pa) { px = d_in[0]; pw = d_in[1]; pa = d_in[2]; }

  const float* x    = (const float*)px;
  const int*   wids = (const int*)pw;
  const float* A    = (const float*)pa;
  float* out = (float*)d_out;
  (void)out_size;

  // ws layout: cnt 64 int (1 KB) | bin 64*2048 u16 (256 KB, pad 512 KB) |
  // partials NS*2048*64 f16 (8 MB). ws ~268 MB observed.
  const size_t need = 1024 + 512 * 1024 +
                      (size_t)NS * B_TOT * R_DIM * sizeof(uint16_t);
  if (ws_size >= need) {
    int*      cnt  = (int*)d_ws;
    uint16_t* bin  = (uint16_t*)((char*)d_ws + 1024);
    uint16_t* part = (uint16_t*)((char*)d_ws + 1024 + 512 * 1024);
    k_bin64<<<dim3(NA_DIM), dim3(64), 0, stream>>>(wids, cnt, bin);
    k_lora_mfma6<<<dim3(NA_DIM * NS), dim3(256), 0, stream>>>(x, cnt, bin, A, part);
    k_reduce32v<<<dim3(512), dim3(256), 0, stream>>>(part, out);
  } else {
    k_naive_f32<<<dim3(B_TOT), dim3(256), 0, stream>>>(x, wids, A, out);
  }
}

// Round 19
// 26.046 us; speedup vs baseline: 1.3935x; 1.3935x over previous
//
#include <hip/hip_runtime.h>
#include <stdint.h>

#define B_TOT 2048
#define H_DIM 4096
#define R_DIM 64
#define NA_DIM 64
#define NS 16                    // k-slices
#define KS (H_DIM / NS)          // 256 k per slice
#define LW 132                   // X_lds row stride in u32 words, %32=4
#define X_ELEMS (B_TOT*H_DIM)
#define W_ELEMS (B_TOT)
#define A_ELEMS (NA_DIM*H_DIM*R_DIM)

typedef _Float16 f16x8 __attribute__((ext_vector_type(8)));
typedef float    f32x4 __attribute__((ext_vector_type(4)));

__device__ __forceinline__ uint32_t pkf16(float a, float b) {
  // exact: inputs are fp16-representable, RTZ == RNE == identity
  auto h = __builtin_amdgcn_cvt_pkrtz(a, b);
  union { decltype(h) v; uint32_t u; } cv; cv.v = h; return cv.u;
}

// === EXACT r15 main kernel (empirical best: 25.97 us, absmax 0.03125) ===
// Block (adapter a = bx&63, k-slice ks = bx>>6): GEMM X_a[n x 256] @
// A_a[256 x 64] -> f16 partial slice ks. A-fragments in registers (afr[8]),
// loaded once per block; in-block wave-0 ballot scan (overlaps other waves'
// A-gather); X staged per 16-sample group as f16 [m][k]; fragment
// (lane,elem)->k maps identical for X and A; C/D col=l&15 (->r=w*16+col),
// row=(l>>4)*4+i (->sample).
__global__ __launch_bounds__(256, 4)
void k_lora_mfma3(const float* __restrict__ x, const int* __restrict__ wids,
                  const float* __restrict__ A, uint16_t* __restrict__ part) {
  __shared__ __align__(16) uint32_t X_lds[16 * LW];     // 8.4 KB
  __shared__ uint16_t sbin[B_TOT];                      // 4 KB
  __shared__ int sn;

  const int bx = blockIdx.x;
  const int a = bx & 63, ks = bx >> 6;
  const int t = threadIdx.x;
  const int w = t >> 6, l = t & 63;
  const int ml = l & 15;    // X-row / D-col lane index
  const int kg = l >> 4;    // k-group within fragment

  // ---- A-fragments -> registers (one-time; reused every M-group) ----
  const float* Abase = A + ((size_t)a * H_DIM + (size_t)ks * KS) * R_DIM
                         + (size_t)(w * 16 + ml);
  f16x8 afr[8];
#pragma unroll
  for (int kst = 0; kst < 8; ++kst) {
    const float* p = Abase + (size_t)(kst * 32 + kg * 8) * R_DIM;
    float v0 = p[0],   v1 = p[64],  v2 = p[128], v3 = p[192];
    float v4 = p[256], v5 = p[320], v6 = p[384], v7 = p[448];
    union { uint4 u; f16x8 h; } cv;
    cv.u.x = pkf16(v0, v1); cv.u.y = pkf16(v2, v3);
    cv.u.z = pkf16(v4, v5); cv.u.w = pkf16(v6, v7);
    afr[kst] = cv.h;
  }

  // ---- wave 0: ballot-scan wids -> ordered sample list ----
  if (w == 0) {
    int v[32];
#pragma unroll
    for (int i = 0; i < 32; ++i) v[i] = wids[i * 64 + l];
    int cnt = 0;
#pragma unroll
    for (int i = 0; i < 32; ++i) {
      bool hit = (v[i] == a);
      unsigned long long m = __ballot(hit);
      if (hit) sbin[cnt + __popcll(m & ((1ull << l) - 1ull))] = (uint16_t)(i * 64 + l);
      cnt += __popcll(m);
    }
    if (l == 0) sn = cnt;
  }
  __syncthreads();   // sbin ready
  const int n = sn;
  if (n == 0) return;

  const int m_st = t >> 4, q_st = t & 15;   // X staging roles

  for (int mg = 0; mg * 16 < n; ++mg) {
    const int base = mg * 16;
    // ---- stage x: 16 rows x 256 k f32 -> f16 [m][k] (coalesced) ----
    {
      int sidx = base + m_st; if (sidx > n - 1) sidx = n - 1;
      const float* xr = x + (size_t)sbin[sidx] * H_DIM + (size_t)ks * KS;
#pragma unroll
      for (int j = 0; j < 2; ++j) {
        const int c = q_st + j * 16;          // 8-elem chunk id
        const int k = c * 8;
        float4 u0 = *(const float4*)(xr + k);
        float4 u1 = *(const float4*)(xr + k + 4);
        uint4 pw;
        pw.x = pkf16(u0.x, u0.y); pw.y = pkf16(u0.z, u0.w);
        pw.z = pkf16(u1.x, u1.y); pw.w = pkf16(u1.z, u1.w);
        *(uint4*)&X_lds[m_st * LW + c * 4] = pw;
      }
    }
    __syncthreads();   // X ready

    // ---- 8 x mfma_f32_16x16x32_f16; A operand straight from registers ----
    f32x4 acc = {0.f, 0.f, 0.f, 0.f};
#pragma unroll
    for (int kst = 0; kst < 8; ++kst) {
      f16x8 xf = *(const f16x8*)(X_lds + ml * LW + kst * 16 + kg * 4);
      acc = __builtin_amdgcn_mfma_f32_16x16x32_f16(xf, afr[kst], acc, 0, 0, 0);
    }

    // ---- store f16 partial: col=ml (->r=w*16+ml), row=kg*4+i (->sample) ----
#pragma unroll
    for (int i = 0; i < 4; ++i) {
      const int sidx = base + kg * 4 + i;
      if (sidx < n) {
        union { _Float16 h; uint16_t u; } cv; cv.h = (_Float16)acc[i];
        part[(size_t)ks * (B_TOT * R_DIM) +
             (size_t)sbin[sidx] * R_DIM + w * 16 + ml] = cv.u;
      }
    }
    if ((mg + 1) * 16 < n) __syncthreads();   // X_lds reads done before restage
  }
}

// Reduce, occupancy-fixed: 512 blocks (2 blocks/CU), one f32 out-elem per
// thread, fixed slice order (bit-identical to r15's k_reduce16h output).
__global__ __launch_bounds__(256)
void k_reduce16v(const uint16_t* __restrict__ part, float* __restrict__ out) {
  const int t = blockIdx.x * 256 + threadIdx.x;   // 131072 threads
  float v = 0.f;
#pragma unroll
  for (int p = 0; p < NS; ++p) {
    union { uint16_t u; _Float16 h; } c;
    c.u = part[(size_t)p * (B_TOT * R_DIM) + t];
    v += (float)c.h;
  }
  out[t] = v;
}

// No-workspace fallback (proven-correct round-6 naive kernel).
__global__ __launch_bounds__(256)
void k_naive_f32(const float* __restrict__ x, const int* __restrict__ wids,
                 const float* __restrict__ A, float* __restrict__ out) {
  __shared__ float red[256];
  const int b = blockIdx.x;
  const int t = threadIdx.x;
  const int r = t & 63;
  const int q = t >> 6;
  const int a = wids[b];
  const float* xrow = x + (size_t)b * H_DIM;
  const float* Aad  = A + (size_t)a * H_DIM * R_DIM + r;
  float acc = 0.f;
  const int h0 = q * (H_DIM / 4), h1 = h0 + (H_DIM / 4);
  for (int h = h0; h < h1; ++h) acc += xrow[h] * Aad[(size_t)h * R_DIM];
  red[t] = acc;
  __syncthreads();
  if (t < 64) {
    out[(size_t)b * R_DIM + t] = red[t] + red[t + 64] + red[t + 128] + red[t + 192];
  }
}

extern "C" void kernel_launch(void* const* d_in, const int* in_sizes, int n_in,
                              void* d_out, int out_size, void* d_ws, size_t ws_size,
                              hipStream_t stream) {
  // Identify inputs by element count — robust to any ordering.
  const void* px = nullptr; const void* pw = nullptr; const void* pa = nullptr;
  for (int i = 0; i < n_in; ++i) {
    if (in_sizes[i] == X_ELEMS) px = d_in[i];
    else if (in_sizes[i] == W_ELEMS) pw = d_in[i];
    else if (in_sizes[i] == A_ELEMS) pa = d_in[i];
  }
  if (!px || !pw || !pa) { px = d_in[0]; pw = d_in[1]; pa = d_in[2]; }

  const float* x    = (const float*)px;
  const int*   wids = (const int*)pw;
  const float* A    = (const float*)pa;
  float* out = (float*)d_out;
  (void)out_size;

  const size_t need = (size_t)NS * B_TOT * R_DIM * sizeof(uint16_t);  // 4 MB (ws ~268 MB)
  if (ws_size >= need) {
    uint16_t* part = (uint16_t*)d_ws;
    k_lora_mfma3<<<dim3(NA_DIM * NS), dim3(256), 0, stream>>>(x, wids, A, part);
    k_reduce16v<<<dim3(512), dim3(256), 0, stream>>>(part, out);
  } else {
    k_naive_f32<<<dim3(B_TOT), dim3(256), 0, stream>>>(x, wids, A, out);
  }
}